// Round 6
// baseline (614.283 us; speedup 1.0000x reference)
//
#include <hip/hip_runtime.h>
#include <stdint.h>

#define N_ENTC   100000
#define N_ROWC   30000
#define K_INSTC  8
#define N_EDGEC  200000
#define N_RELSC  200          // rel_full has 201 rows (loop_rel appended)
#define NTOTC    (N_ENTC + N_ROWC)   // 130000
#define CAPB     64           // bucket capacity per target entity (deg~Poisson(2))

typedef _Float16 half8  __attribute__((ext_vector_type(8)));
typedef _Float16 half4v __attribute__((ext_vector_type(4)));
typedef float    float4v __attribute__((ext_vector_type(4)));

// ---------------------------------------------------------------------------
// K1: per-relation-type table  s_edge_tab[t][j] = e_mean_t . W_sheaf[128:,j] + b_sheaf[j]
//     and r_out = rel_embed @ w_rel  (written straight to d_out tail, fp32)
// ---------------------------------------------------------------------------
__global__ __launch_bounds__(256) void k_rel(
    const float* __restrict__ rel_embed, const float* __restrict__ loop_rel,
    const float* __restrict__ W_edge,    const float* __restrict__ b_edge,
    const float* __restrict__ W_sheaf,   const float* __restrict__ b_sheaf,
    const float* __restrict__ w_rel,
    float* __restrict__ s_edge_tab, float* __restrict__ out_rel)
{
  __shared__ float rel[256];
  __shared__ float eproj[256];
  __shared__ float em[128];
  int t = blockIdx.x;        // 0..200
  int c = threadIdx.x;       // 0..255
  rel[c] = (t < N_RELSC) ? rel_embed[t * 256 + c] : loop_rel[c];
  __syncthreads();
  float acc = b_edge[c];
  for (int k = 0; k < 256; ++k) acc += rel[k] * W_edge[k * 256 + c];
  eproj[c] = acc;
  __syncthreads();
  if (c < 128) em[c] = 0.5f * (eproj[c] + eproj[c + 128]);
  __syncthreads();
  if (c < 2) {
    float s = b_sheaf[c];
    for (int hh = 0; hh < 128; ++hh) s += em[hh] * W_sheaf[(128 + hh) * 2 + c];
    s_edge_tab[t * 2 + c] = s;
  }
  if (t < N_RELSC) {
    float ro = 0.f;
    for (int k = 0; k < 256; ++k) ro += rel[k] * w_rel[k * 256 + c];
    out_rel[t * 256 + c] = ro;
  }
}

// ---------------------------------------------------------------------------
// K_fuse: fold the two linear layers into one weight matrix.
//   W_comb[k][n] = sum_c W_in[k][ (n>>7)*128 + c ] * W_conv[c][ n&127 ]
//   b_comb[n]   = (b_in @ blockdiag(W_conv))[n] + b_conv[n&127]
//   w_s[k][j]   = sum_hh 0.5*(W_in[k][hh]+W_in[k][hh+128]) * W_sheaf[hh][j]
//   c_s[j]      = same with b_in                      (stored at w_s[512+j])
// W_comb is split fp16 hi/lo and stored in MFMA B-fragment layout:
//   frag(kt,ntile): lane l holds B[kt*32 + 8*(l>>4)+e][ntile*16 + (l&15)],
//   element offset = ((kt*16+ntile)*64 + l)*8 + e.
// ---------------------------------------------------------------------------
__global__ __launch_bounds__(256) void k_fuse(
    const float* __restrict__ W_in,  const float* __restrict__ b_in,
    const float* __restrict__ W_conv, const float* __restrict__ b_conv,
    const float* __restrict__ W_sheaf,
    _Float16* __restrict__ Whi, _Float16* __restrict__ Wlo,
    float* __restrict__ b_comb, float* __restrict__ w_s)
{
  __shared__ float win[256];
  int k = blockIdx.x;            // 0..256
  int n = threadIdx.x;           // 0..255
  const float* src = (k < 256) ? (W_in + (size_t)k * 256) : b_in;
  win[n] = src[n];
  __syncthreads();
  int j = n >> 7, hh = n & 127;
  float acc = 0.f;
  for (int c = 0; c < 128; ++c)
    acc += win[j * 128 + c] * W_conv[c * 128 + hh];
  if (k < 256) {
    _Float16 hi = (_Float16)acc;
    _Float16 lo = (_Float16)(acc - (float)hi);
    int kt = k >> 5, g = (k >> 3) & 3, e = k & 7;
    int idx = ((kt * 16 + (n >> 4)) * 64 + (g * 16 + (n & 15))) * 8 + e;
    Whi[idx] = hi; Wlo[idx] = lo;
    if (n < 2) {
      float s = 0.f;
      for (int c2 = 0; c2 < 128; ++c2)
        s += 0.5f * (win[c2] + win[c2 + 128]) * W_sheaf[c2 * 2 + n];
      w_s[k * 2 + n] = s;
    }
  } else {
    b_comb[n] = acc + b_conv[hh];
    if (n < 2) {
      float s = 0.f;
      for (int c2 = 0; c2 < 128; ++c2)
        s += 0.5f * (win[c2] + win[c2 + 128]) * W_sheaf[c2 * 2 + n];
      w_s[512 + n] = s;          // c_s
    }
  }
}

// ---------------------------------------------------------------------------
// K_gemm: h[0:N_ENTC] = x @ W_comb + b_comb via fp16 split-precision MFMA,
//   PLUS fused s_node[0:N_ENTC] = x . w_s + c_s computed from the fp32
//   staging values (free VALU; 16-lane shuffle reduce at the end).
//   Instance rows are NOT computed here: by linearity they are masked means
//   of entity rows (see k_hinst).
//   Epilogue stages each 16x256 slice through LDS (XOR swizzle col^(g<<4),
//   2-way conflict = free) -> fully coalesced 1KB/wave float4 stores.
// ---------------------------------------------------------------------------
__global__ __launch_bounds__(256, 3) void k_gemm(
    const float* __restrict__ x,
    const _Float16* __restrict__ Whi, const _Float16* __restrict__ Wlo,
    const float* __restrict__ b_comb, const float* __restrict__ w_s,
    float* __restrict__ h, float* __restrict__ s_node)
{
  __shared__ union {
    struct { _Float16 Ahi[64 * 64]; _Float16 Alo[64 * 64]; } a;  // 16 KB
    float ep[16 * 256];                                          // 16 KB
  } sm;
  __shared__ float wsl[514];

  int tid = threadIdx.x;
  for (int i = tid; i < 514; i += 256) wsl[i] = w_s[i];
  __syncthreads();

  int l = tid & 63;            // lane
  int w = tid >> 6;            // wave 0..3 -> col stripe w*64
  int row0 = blockIdx.x * 64;
  int g = l >> 4;              // fragment k-group
  int cn = l & 15;             // fragment row/col within 16

  float4v acc[4][4];
#pragma unroll
  for (int a = 0; a < 4; ++a)
#pragma unroll
    for (int b = 0; b < 4; ++b) acc[a][b] = (float4v)(0.f);

  int rs = tid >> 4;           // staging: row residue 0..15
  int kb = (tid & 15) * 4;     // staging: 4-float k chunk
  float sn0[4], sn1[4];
#pragma unroll
  for (int i = 0; i < 4; ++i) { sn0[i] = 0.f; sn1[i] = 0.f; }

  for (int ks = 0; ks < 4; ++ks) {
    int k0 = ks * 64;
    // ---- stage A tile (64 rows x 64 k), fp32 -> fp16 hi/lo, swizzled ----
#pragma unroll
    for (int i = 0; i < 4; ++i) {
      int r = rs + i * 16;
      int row = row0 + r;
      float4 v = make_float4(0.f, 0.f, 0.f, 0.f);
      if (row < N_ENTC) {
        v = *(const float4*)(x + (size_t)row * 256 + k0 + kb);
      }
      // fused s_node partial (fp32, exact staging values)
      int k2 = (k0 + kb) * 2;
      sn0[i] += v.x * wsl[k2 + 0] + v.y * wsl[k2 + 2]
              + v.z * wsl[k2 + 4] + v.w * wsl[k2 + 6];
      sn1[i] += v.x * wsl[k2 + 1] + v.y * wsl[k2 + 3]
              + v.z * wsl[k2 + 5] + v.w * wsl[k2 + 7];
      half4v hv, lv;
      hv[0] = (_Float16)v.x; lv[0] = (_Float16)(v.x - (float)hv[0]);
      hv[1] = (_Float16)v.y; lv[1] = (_Float16)(v.y - (float)hv[1]);
      hv[2] = (_Float16)v.z; lv[2] = (_Float16)(v.z - (float)hv[2]);
      hv[3] = (_Float16)v.w; lv[3] = (_Float16)(v.w - (float)hv[3]);
      int idx = r * 64 + (((kb >> 3) ^ (r & 7)) << 3) + (kb & 7);
      *(half4v*)&sm.a.Ahi[idx] = hv;
      *(half4v*)&sm.a.Alo[idx] = lv;
    }
    __syncthreads();
    // ---- compute ----
#pragma unroll
    for (int kf = 0; kf < 2; ++kf) {
      int kt = ks * 2 + kf;
      half8 ah[4], al[4];
#pragma unroll
      for (int mt = 0; mt < 4; ++mt) {
        int row = mt * 16 + cn;
        int slot = (kf * 4 + g) ^ (cn & 7);
        int aidx = row * 64 + slot * 8;
        ah[mt] = *(const half8*)&sm.a.Ahi[aidx];
        al[mt] = *(const half8*)&sm.a.Alo[aidx];
      }
#pragma unroll
      for (int nt = 0; nt < 4; ++nt) {
        size_t boff = ((size_t)(kt * 16 + w * 4 + nt) * 64 + l) * 8;
        half8 bh = *(const half8*)(Whi + boff);
        half8 bl = *(const half8*)(Wlo + boff);
#pragma unroll
        for (int mt = 0; mt < 4; ++mt) {
          acc[mt][nt] = __builtin_amdgcn_mfma_f32_16x16x32_f16(ah[mt], bh, acc[mt][nt], 0, 0, 0);
          acc[mt][nt] = __builtin_amdgcn_mfma_f32_16x16x32_f16(al[mt], bh, acc[mt][nt], 0, 0, 0);
          acc[mt][nt] = __builtin_amdgcn_mfma_f32_16x16x32_f16(ah[mt], bl, acc[mt][nt], 0, 0, 0);
        }
      }
    }
    __syncthreads();
  }

  // ---- s_node write: reduce over the 16 lanes sharing rs (low-4 tid bits) ----
#pragma unroll
  for (int i = 0; i < 4; ++i) {
    float a0 = sn0[i], a1 = sn1[i];
#pragma unroll
    for (int m = 1; m <= 8; m <<= 1) {
      a0 += __shfl_xor(a0, m);
      a1 += __shfl_xor(a1, m);
    }
    int row = row0 + rs + i * 16;
    if ((tid & 15) == 0 && row < N_ENTC) {
      s_node[(size_t)row * 2 + 0] = a0 + wsl[512];
      s_node[(size_t)row * 2 + 1] = a1 + wsl[513];
    }
  }

  // ---- epilogue: LDS-staged coalesced store of h (+b_comb) ----
  float bc[4];
#pragma unroll
  for (int nt = 0; nt < 4; ++nt) bc[nt] = b_comb[w * 64 + nt * 16 + cn];
#pragma unroll
  for (int mt = 0; mt < 4; ++mt) {
    __syncthreads();
#pragma unroll
    for (int nt = 0; nt < 4; ++nt)
#pragma unroll
      for (int rr = 0; rr < 4; ++rr) {
        int row = g * 4 + rr;                    // 0..15 within slice
        int col = w * 64 + nt * 16 + cn;
        int colp = col ^ (g << 4);               // bank swizzle (2-way = free)
        sm.ep[row * 256 + colp] = acc[mt][nt][rr] + bc[nt];
      }
    __syncthreads();
    int gr = row0 + mt * 16;
#pragma unroll
    for (int q = 0; q < 4; ++q) {
      int f = tid + q * 256;
      int row = f >> 6, c4 = (f & 63) * 4;
      int colp = c4 ^ (((row >> 2) & 3) << 4);
      float4 vv = *(float4*)&sm.ep[row * 256 + colp];
      int grow = gr + row;
      if (grow < N_ENTC)
        *(float4*)&h[(size_t)grow * 256 + c4] = vv;
    }
  }
}

// ---------------------------------------------------------------------------
// K_hinst: by linearity, instance rows are masked means of entity rows:
//   h[N+r]      = mean_{id valid} h[id]       (b_comb averages to itself)
//   s_node[N+r] = mean_{id valid} s_node[id]
// 4 rows/block, one wave per row, lane owns 4 channels (float4 gathers).
// ids are wave-uniform -> no divergence; 8 gather addresses independent.
// ---------------------------------------------------------------------------
__global__ __launch_bounds__(256) void k_hinst(
    float* __restrict__ h, float* __restrict__ s_node,
    const int* __restrict__ ids)
{
  int tid = threadIdx.x;
  int r = blockIdx.x * 4 + (tid >> 6);
  int l = tid & 63;
  int ch = l * 4;
  if (r >= N_ROWC) return;
  float4 s = make_float4(0.f, 0.f, 0.f, 0.f);
  float sn0 = 0.f, sn1 = 0.f;
  int cnt = 0;
#pragma unroll
  for (int k = 0; k < K_INSTC; ++k) {
    int id = ids[r * K_INSTC + k];
    if (id >= 0) {
      float4 v = *(const float4*)(h + (size_t)id * 256 + ch);
      s.x += v.x; s.y += v.y; s.z += v.z; s.w += v.w;
      if (l == 0) {
        sn0 += s_node[(size_t)id * 2 + 0];
        sn1 += s_node[(size_t)id * 2 + 1];
      }
      cnt++;
    }
  }
  float inv = 1.f / (float)cnt;   // cnt >= 1 guaranteed
  float4 o; o.x = s.x * inv; o.y = s.y * inv; o.z = s.z * inv; o.w = s.w * inv;
  *(float4*)(h + (size_t)(N_ENTC + r) * 256 + ch) = o;
  if (l == 0) {
    s_node[(size_t)(N_ENTC + r) * 2 + 0] = sn0 * inv;
    s_node[(size_t)(N_ENTC + r) * 2 + 1] = sn1 * inv;
  }
}

// ---------------------------------------------------------------------------
// K4a: per-edge alphas (tanh), Dn scatter, and packed bucket fill.
//   bE[slot] = {instRow, 0, bits(0.5*a10*a20), bits(0.5*a11*a21)} (one 16B slot)
//   Self term (0.5*a2^2*h_t) is folded analytically into k_gather.
// ---------------------------------------------------------------------------
__global__ __launch_bounds__(256) void k_alpha(
    const int* __restrict__ ei0, const int* __restrict__ ei1,
    const int* __restrict__ etype,
    const float* __restrict__ s_node, const float* __restrict__ s_edge_tab,
    float* __restrict__ Dn, int* __restrict__ cnt,
    int4* __restrict__ bE)
{
  int e = blockIdx.x * 256 + threadIdx.x;
  if (e >= N_EDGEC) return;
  int t = ei0[e], rI = ei1[e], ty = etype[e];
  float se0 = s_edge_tab[ty * 2 + 0], se1 = s_edge_tab[ty * 2 + 1];
  const float* snI = &s_node[(size_t)(N_ENTC + rI) * 2];
  const float* snT = &s_node[(size_t)t * 2];
  float a10 = tanhf(snI[0] + se0);
  float a11 = tanhf(snI[1] + se1);
  float a20 = tanhf(snT[0] + se0);
  float a21 = tanhf(snT[1] + se1);
  atomicAdd(&Dn[t * 2 + 0], a20 * a20);
  atomicAdd(&Dn[t * 2 + 1], a21 * a21);
  int pos = atomicAdd(&cnt[t], 1);
  if (pos < CAPB) {
    int4 ee;
    ee.x = rI; ee.y = 0;
    ee.z = __float_as_int(0.5f * a10 * a20);
    ee.w = __float_as_int(0.5f * a11 * a21);
    bE[(size_t)t * CAPB + pos] = ee;
  }
}

// ---------------------------------------------------------------------------
// K_gather: fused diffusion gather + finalize.
//   out = Dinv * sum_e c_j * h[instRow] + (dn>0 ? 1.5 : 1.0)*h_t + conv_bias
//   -> ELU -> + mod_bias -> prebn stored IN PLACE into h[:N].
// 4 waves/block, each wave sequentially owns EPB/4 entities; lane owns 4
// channels (float4). EPB=32 -> 3125 blocks = 12.5K independent latency
// chains. BN stats: per-thread doubles -> LDS cross-wave reduce -> 512
// atomics/block.
// ---------------------------------------------------------------------------
#define EPB 32    // entities per block (8 per wave)
__global__ __launch_bounds__(256) void k_gather(
    float* h, const float* __restrict__ Dn,
    const int* __restrict__ cnt, const int4* __restrict__ bE,
    const float* __restrict__ conv_bias, const float* __restrict__ mod_bias,
    double* __restrict__ bnacc)
{
  __shared__ double red[4][512];
  int tid = threadIdx.x;
  int wv = tid >> 6, l = tid & 63;
  int ch = l * 4;                 // base channel 0..252
  int j = l >> 5;                 // head
  float4 cb = *(const float4*)(conv_bias + (ch & 127));
  float4 mb = *(const float4*)(mod_bias + ch);
  double s0 = 0, s1 = 0, s2 = 0, s3 = 0;
  double q0 = 0, q1 = 0, q2 = 0, q3 = 0;
  int tbase = blockIdx.x * EPB + wv * (EPB / 4);
  for (int i = 0; i < EPB / 4; ++i) {
    int t = tbase + i;
    if (t >= N_ENTC) break;
    int deg = cnt[t]; deg = (deg < CAPB) ? deg : CAPB;
    float dn = Dn[t * 2 + j];
    float dinv = (dn > 0.f) ? (1.0f / dn) : 0.f;
    float sf = (dn > 0.f) ? 1.5f : 1.0f;     // 0.5*ht self-term + residual ht
    float4 cr = make_float4(0.f, 0.f, 0.f, 0.f);
    const int4* be = bE + (size_t)t * CAPB;
    for (int k = 0; k < deg; ++k) {
      int4 ee = be[k];
      float c = (l < 32) ? __int_as_float(ee.z) : __int_as_float(ee.w);
      float4 hv = *(const float4*)(h + (size_t)(N_ENTC + ee.x) * 256 + ch);
      cr.x += c * hv.x; cr.y += c * hv.y; cr.z += c * hv.z; cr.w += c * hv.w;
    }
    size_t idx = (size_t)t * 256 + ch;
    float4 ht = *(const float4*)(h + idx);
    float4 o;
    o.x = dinv * cr.x + sf * ht.x + cb.x;
    o.y = dinv * cr.y + sf * ht.y + cb.y;
    o.z = dinv * cr.z + sf * ht.z + cb.z;
    o.w = dinv * cr.w + sf * ht.w + cb.w;
    o.x = (o.x > 0.f) ? o.x : expm1f(o.x);
    o.y = (o.y > 0.f) ? o.y : expm1f(o.y);
    o.z = (o.z > 0.f) ? o.z : expm1f(o.z);
    o.w = (o.w > 0.f) ? o.w : expm1f(o.w);
    o.x += mb.x; o.y += mb.y; o.z += mb.z; o.w += mb.w;
    *(float4*)(h + idx) = o;                 // prebn in place
    s0 += (double)o.x; q0 += (double)o.x * (double)o.x;
    s1 += (double)o.y; q1 += (double)o.y * (double)o.y;
    s2 += (double)o.z; q2 += (double)o.z * (double)o.z;
    s3 += (double)o.w; q3 += (double)o.w * (double)o.w;
  }
  red[wv][ch + 0] = s0; red[wv][ch + 1] = s1;
  red[wv][ch + 2] = s2; red[wv][ch + 3] = s3;
  red[wv][256 + ch + 0] = q0; red[wv][256 + ch + 1] = q1;
  red[wv][256 + ch + 2] = q2; red[wv][256 + ch + 3] = q3;
  __syncthreads();
  double ssum = red[0][tid] + red[1][tid] + red[2][tid] + red[3][tid];
  double qsum = red[0][256 + tid] + red[1][256 + tid]
              + red[2][256 + tid] + red[3][256 + tid];
  atomicAdd(&bnacc[tid], ssum);
  atomicAdd(&bnacc[256 + tid], qsum);
}

// ---------------------------------------------------------------------------
// K6: BN affine coefficients (biased var, eps=1e-5)
// ---------------------------------------------------------------------------
__global__ void k_bnstat(const double* __restrict__ bnacc,
                         const float* __restrict__ gamma, const float* __restrict__ beta,
                         float* __restrict__ ss)
{
  int c = threadIdx.x;
  double mu  = bnacc[c] / (double)N_ENTC;
  double var = bnacc[256 + c] / (double)N_ENTC - mu * mu;
  double istd = 1.0 / sqrt(var + 1e-5);
  float sc = (float)((double)gamma[c] * istd);
  float sh = (float)((double)beta[c] - mu * (double)sc);
  ss[c] = sc; ss[256 + c] = sh;
}

// ---------------------------------------------------------------------------
// K7: normalize + fp32 store of out_ent  (prebn lives in h[:N])
// ---------------------------------------------------------------------------
__global__ __launch_bounds__(256) void k_store(
    const float* __restrict__ prebn, const float* __restrict__ ss,
    float* __restrict__ out)
{
  size_t stride = (size_t)gridDim.x * 256 * 4;
  for (size_t i = ((size_t)blockIdx.x * 256 + threadIdx.x) * 4;
       i < (size_t)N_ENTC * 256; i += stride) {
    float4 a = *(const float4*)(prebn + i);
    int c = (int)(i & 255);
    float4 o;
    o.x = a.x * ss[c + 0] + ss[256 + c + 0];
    o.y = a.y * ss[c + 1] + ss[256 + c + 1];
    o.z = a.z * ss[c + 2] + ss[256 + c + 2];
    o.w = a.w * ss[c + 3] + ss[256 + c + 3];
    *(float4*)(out + i) = o;
  }
}

// ---------------------------------------------------------------------------
// Workspace layout (unchanged offsets; inst buffer no longer used):
//   h       [0, 133,120,000)              fp32; [0:N) entity rows (-> prebn),
//                                         [N:NTOT) instance rows (k_hinst)
//   Dn      [133,120,000, +800,000)       zeroed by memset #1
//   bnacc   [133,920,000, +4,096)         zeroed by memset #1
//   cnt     [133,924,096, +400,000)       zeroed by memset #1
//   s_node  [134,324,096, +1,040,000)
//   ss      [135,364,096, +2,048)
//   s_edge  [135,366,144, +2,048)
//   BIG     [135,368,192, +102,400,000)
//     phase A (until k_gemm done):
//       Whi    @ +30,720,000 (131,072)
//       Wlo    @ +30,851,072 (131,072)
//       b_comb @ +30,982,144 (1,024)
//       w_s    @ +30,983,168 (2,064)
//     phase B (k_alpha onward; phase A dead):
//       bE     @ +0          (102,400,000)  int4[100K*64] packed {rI,_,c0,c1}
// ---------------------------------------------------------------------------
extern "C" void kernel_launch(void* const* d_in, const int* in_sizes, int n_in,
                              void* d_out, int out_size, void* d_ws, size_t ws_size,
                              hipStream_t stream)
{
  (void)in_sizes; (void)n_in; (void)out_size; (void)ws_size;

  const float* x         = (const float*)d_in[0];
  const int*   edge_idx  = (const int*)d_in[1];
  // d_in[2] = edge_order (unused)
  const int*   etype     = (const int*)d_in[3];
  const float* rel_embed = (const float*)d_in[4];
  const int*   ids       = (const int*)d_in[5];
  const float* W_in      = (const float*)d_in[6];
  const float* b_in      = (const float*)d_in[7];
  const float* W_edge    = (const float*)d_in[8];
  const float* b_edge    = (const float*)d_in[9];
  const float* W_sheaf   = (const float*)d_in[10];
  const float* b_sheaf   = (const float*)d_in[11];
  const float* W_conv    = (const float*)d_in[12];
  const float* b_conv    = (const float*)d_in[13];
  const float* conv_bias = (const float*)d_in[14];
  const float* w_rel     = (const float*)d_in[15];
  const float* loop_rel  = (const float*)d_in[16];
  const float* mod_bias  = (const float*)d_in[17];
  const float* bn_gamma  = (const float*)d_in[18];
  const float* bn_beta   = (const float*)d_in[19];

  const int* ei0 = edge_idx;            // target entities
  const int* ei1 = edge_idx + N_EDGEC;  // source instance rows

  char* ws = (char*)d_ws;
  const size_t OFF_H     = 0;
  const size_t OFF_DN    = OFF_H     + (size_t)NTOTC * 256 * 4;   // 133,120,000
  const size_t OFF_BN    = OFF_DN    + (size_t)N_ENTC * 2 * 4;    // +800,000
  const size_t OFF_CNT   = OFF_BN    + 4096;
  const size_t OFF_SNODE = OFF_CNT   + (size_t)N_ENTC * 4;
  const size_t OFF_SS    = OFF_SNODE + (size_t)NTOTC * 2 * 4;
  const size_t OFF_SEDGE = OFF_SS    + 2048;
  const size_t OFF_BIG   = OFF_SEDGE + 2048;
  const size_t OFF_WHI   = OFF_BIG   + (size_t)N_ROWC * 256 * 4;
  const size_t OFF_WLO   = OFF_WHI   + 131072;
  const size_t OFF_BC    = OFF_WLO   + 131072;
  const size_t OFF_WS    = OFF_BC    + 1024;
  const size_t OFF_BE    = OFF_BIG;                               // phase B

  float*     h       = (float*)(ws + OFF_H);
  float*     Dn      = (float*)(ws + OFF_DN);
  double*    bnacc   = (double*)(ws + OFF_BN);
  int*       cnt     = (int*)(ws + OFF_CNT);
  float*     s_node  = (float*)(ws + OFF_SNODE);
  float*     ss      = (float*)(ws + OFF_SS);
  float*     s_edge  = (float*)(ws + OFF_SEDGE);
  _Float16*  Whi     = (_Float16*)(ws + OFF_WHI);
  _Float16*  Wlo     = (_Float16*)(ws + OFF_WLO);
  float*     b_comb  = (float*)(ws + OFF_BC);
  float*     w_s     = (float*)(ws + OFF_WS);
  int4*      bE      = (int4*)(ws + OFF_BE);     // phase B overlay

  float* out_ent = (float*)d_out;
  float* out_rel = (float*)d_out + (size_t)N_ENTC * 256;

  // memset #1: Dn + bnacc + cnt (contiguous)
  hipMemsetAsync(ws + OFF_DN, 0,
                 (size_t)N_ENTC * 2 * 4 + 4096 + (size_t)N_ENTC * 4, stream);

  k_rel<<<201, 256, 0, stream>>>(rel_embed, loop_rel, W_edge, b_edge,
                                 W_sheaf, b_sheaf, w_rel, s_edge, out_rel);
  k_fuse<<<257, 256, 0, stream>>>(W_in, b_in, W_conv, b_conv, W_sheaf,
                                  Whi, Wlo, b_comb, w_s);
  k_gemm<<<(N_ENTC + 63) / 64, 256, 0, stream>>>(x, Whi, Wlo, b_comb, w_s,
                                                 h, s_node);
  k_hinst<<<(N_ROWC + 3) / 4, 256, 0, stream>>>(h, s_node, ids);

  k_alpha<<<(N_EDGEC + 255) / 256, 256, 0, stream>>>(ei0, ei1, etype,
                                                     s_node, s_edge,
                                                     Dn, cnt, bE);
  k_gather<<<(N_ENTC + EPB - 1) / EPB, 256, 0, stream>>>(h, Dn, cnt, bE,
                                                         conv_bias, mod_bias,
                                                         bnacc);
  k_bnstat<<<1, 256, 0, stream>>>(bnacc, bn_gamma, bn_beta, ss);
  k_store<<<8192, 256, 0, stream>>>(h, ss, out_ent);
}

// Round 7
// 537.406 us; speedup vs baseline: 1.1431x; 1.1431x over previous
//
#include <hip/hip_runtime.h>
#include <stdint.h>

#define N_ENTC   100000
#define N_ROWC   30000
#define K_INSTC  8
#define N_EDGEC  200000
#define N_RELSC  200          // rel_full has 201 rows (loop_rel appended)
#define NTOTC    (N_ENTC + N_ROWC)   // 130000
#define CAPB     64           // bucket capacity per target entity (deg~Poisson(2))

typedef _Float16 half8  __attribute__((ext_vector_type(8)));
typedef _Float16 half4v __attribute__((ext_vector_type(4)));
typedef float    float4v __attribute__((ext_vector_type(4)));

// ---------------------------------------------------------------------------
// K1: per-relation-type table  s_edge_tab[t][j] = e_mean_t . W_sheaf[128:,j] + b_sheaf[j]
//     and r_out = rel_embed @ w_rel  (written straight to d_out tail, fp32)
// ---------------------------------------------------------------------------
__global__ __launch_bounds__(256) void k_rel(
    const float* __restrict__ rel_embed, const float* __restrict__ loop_rel,
    const float* __restrict__ W_edge,    const float* __restrict__ b_edge,
    const float* __restrict__ W_sheaf,   const float* __restrict__ b_sheaf,
    const float* __restrict__ w_rel,
    float* __restrict__ s_edge_tab, float* __restrict__ out_rel)
{
  __shared__ float rel[256];
  __shared__ float eproj[256];
  __shared__ float em[128];
  int t = blockIdx.x;        // 0..200
  int c = threadIdx.x;       // 0..255
  rel[c] = (t < N_RELSC) ? rel_embed[t * 256 + c] : loop_rel[c];
  __syncthreads();
  float acc = b_edge[c];
  for (int k = 0; k < 256; ++k) acc += rel[k] * W_edge[k * 256 + c];
  eproj[c] = acc;
  __syncthreads();
  if (c < 128) em[c] = 0.5f * (eproj[c] + eproj[c + 128]);
  __syncthreads();
  if (c < 2) {
    float s = b_sheaf[c];
    for (int hh = 0; hh < 128; ++hh) s += em[hh] * W_sheaf[(128 + hh) * 2 + c];
    s_edge_tab[t * 2 + c] = s;
  }
  if (t < N_RELSC) {
    float ro = 0.f;
    for (int k = 0; k < 256; ++k) ro += rel[k] * w_rel[k * 256 + c];
    out_rel[t * 256 + c] = ro;
  }
}

// ---------------------------------------------------------------------------
// K_fuse: fold the two linear layers into one weight matrix.
//   W_comb[k][n] = sum_c W_in[k][ (n>>7)*128 + c ] * W_conv[c][ n&127 ]
//   b_comb[n]   = (b_in @ blockdiag(W_conv))[n] + b_conv[n&127]
//   w_s[k][j]   = sum_hh 0.5*(W_in[k][hh]+W_in[k][hh+128]) * W_sheaf[hh][j]
//   c_s[j]      = same with b_in                      (stored at w_s[512+j])
// W_comb is split fp16 hi/lo and stored in MFMA B-fragment layout:
//   frag(kt,ntile): lane l holds B[kt*32 + 8*(l>>4)+e][ntile*16 + (l&15)],
//   element offset = ((kt*16+ntile)*64 + l)*8 + e.
// ---------------------------------------------------------------------------
__global__ __launch_bounds__(256) void k_fuse(
    const float* __restrict__ W_in,  const float* __restrict__ b_in,
    const float* __restrict__ W_conv, const float* __restrict__ b_conv,
    const float* __restrict__ W_sheaf,
    _Float16* __restrict__ Whi, _Float16* __restrict__ Wlo,
    float* __restrict__ b_comb, float* __restrict__ w_s)
{
  __shared__ float win[256];
  int k = blockIdx.x;            // 0..256
  int n = threadIdx.x;           // 0..255
  const float* src = (k < 256) ? (W_in + (size_t)k * 256) : b_in;
  win[n] = src[n];
  __syncthreads();
  int j = n >> 7, hh = n & 127;
  float acc = 0.f;
  for (int c = 0; c < 128; ++c)
    acc += win[j * 128 + c] * W_conv[c * 128 + hh];
  if (k < 256) {
    _Float16 hi = (_Float16)acc;
    _Float16 lo = (_Float16)(acc - (float)hi);
    int kt = k >> 5, g = (k >> 3) & 3, e = k & 7;
    int idx = ((kt * 16 + (n >> 4)) * 64 + (g * 16 + (n & 15))) * 8 + e;
    Whi[idx] = hi; Wlo[idx] = lo;
    if (n < 2) {
      float s = 0.f;
      for (int c2 = 0; c2 < 128; ++c2)
        s += 0.5f * (win[c2] + win[c2 + 128]) * W_sheaf[c2 * 2 + n];
      w_s[k * 2 + n] = s;
    }
  } else {
    b_comb[n] = acc + b_conv[hh];
    if (n < 2) {
      float s = 0.f;
      for (int c2 = 0; c2 < 128; ++c2)
        s += 0.5f * (win[c2] + win[c2 + 128]) * W_sheaf[c2 * 2 + n];
      w_s[512 + n] = s;          // c_s
    }
  }
}

// ---------------------------------------------------------------------------
// K_snode: s_node[row][j] = x[row] . w_s[:,j] + c_s[j]   (fp32, 2 cols)
// ENTITY ROWS ONLY (instance rows derived in k_hinst by linearity).
// Scheduled BEFORE k_gemm: also serves to warm x into LLC (R5's k_gemm
// FETCH=68MB < |x| came precisely from this warming effect).
// ---------------------------------------------------------------------------
__global__ __launch_bounds__(256) void k_snode(
    const float* __restrict__ x,
    const float* __restrict__ w_s, float* __restrict__ s_node)
{
  __shared__ float ws[514];
  int tid = threadIdx.x;
  for (int i = tid; i < 514; i += 256) ws[i] = w_s[i];
  __syncthreads();
  int r = tid >> 2, q = tid & 3;
  int row = blockIdx.x * 64 + r;
  if (row >= N_ENTC) return;    // whole 4-lane group exits together
  const float* src = x + (size_t)row * 256;
  float s0 = 0.f, s1 = 0.f;
  int kbase = q * 64;
#pragma unroll
  for (int i = 0; i < 16; ++i) {
    float4 v = *(const float4*)(src + kbase + i * 4);
    int k2 = (kbase + i * 4) * 2;
    s0 += v.x * ws[k2 + 0] + v.y * ws[k2 + 2] + v.z * ws[k2 + 4] + v.w * ws[k2 + 6];
    s1 += v.x * ws[k2 + 1] + v.y * ws[k2 + 3] + v.z * ws[k2 + 5] + v.w * ws[k2 + 7];
  }
  s0 += __shfl_xor(s0, 1); s0 += __shfl_xor(s0, 2);
  s1 += __shfl_xor(s1, 1); s1 += __shfl_xor(s1, 2);
  if (q < 2) {
    float val = (q == 0) ? s0 : s1;
    s_node[(size_t)row * 2 + q] = val + ws[512 + q];
  }
}

// ---------------------------------------------------------------------------
// K_gemm: h[0:N_ENTC] = x @ W_comb + b_comb via fp16 split-precision MFMA.
//   3-term Ootomo split: acc += Ahi*Bhi + Alo*Bhi + Ahi*Blo  (~fp32 accuracy)
//   EXACT R5 structure (measured 109us @130K rows, 0 bank conflicts), only
//   restricted to entity rows. R6's LDS-staged epilogue + fused s_node
//   REVERTED: it doubled runtime (WRITE 191->272MB, 1.3e7 conflicts).
// ---------------------------------------------------------------------------
__global__ __launch_bounds__(256, 3) void k_gemm(
    const float* __restrict__ x,
    const _Float16* __restrict__ Whi, const _Float16* __restrict__ Wlo,
    const float* __restrict__ b_comb,
    float* __restrict__ h)
{
  __shared__ _Float16 Ahi[64 * 64];
  __shared__ _Float16 Alo[64 * 64];

  int tid = threadIdx.x;
  int l = tid & 63;            // lane
  int w = tid >> 6;            // wave 0..3 -> col stripe w*64
  int row0 = blockIdx.x * 64;
  int g = l >> 4;              // fragment k-group
  int cn = l & 15;             // fragment row/col within 16

  float4v acc[4][4];
#pragma unroll
  for (int a = 0; a < 4; ++a)
#pragma unroll
    for (int b = 0; b < 4; ++b) acc[a][b] = (float4v)(0.f);

  int rs = tid >> 4;           // staging: row residue 0..15
  int kb = (tid & 15) * 4;     // staging: 4-float k chunk

  for (int ks = 0; ks < 4; ++ks) {
    int k0 = ks * 64;
    // ---- stage A tile (64 rows x 64 k), fp32 -> fp16 hi/lo, swizzled ----
#pragma unroll
    for (int i = 0; i < 4; ++i) {
      int r = rs + i * 16;
      int row = row0 + r;
      float4 v = make_float4(0.f, 0.f, 0.f, 0.f);
      if (row < N_ENTC) {
        v = *(const float4*)(x + (size_t)row * 256 + k0 + kb);
      }
      half4v hv, lv;
      hv[0] = (_Float16)v.x; lv[0] = (_Float16)(v.x - (float)hv[0]);
      hv[1] = (_Float16)v.y; lv[1] = (_Float16)(v.y - (float)hv[1]);
      hv[2] = (_Float16)v.z; lv[2] = (_Float16)(v.z - (float)hv[2]);
      hv[3] = (_Float16)v.w; lv[3] = (_Float16)(v.w - (float)hv[3]);
      int idx = r * 64 + (((kb >> 3) ^ (r & 7)) << 3) + (kb & 7);
      *(half4v*)&Ahi[idx] = hv;
      *(half4v*)&Alo[idx] = lv;
    }
    __syncthreads();
    // ---- compute ----
#pragma unroll
    for (int kf = 0; kf < 2; ++kf) {
      int kt = ks * 2 + kf;
      half8 ah[4], al[4];
#pragma unroll
      for (int mt = 0; mt < 4; ++mt) {
        int row = mt * 16 + cn;
        int slot = (kf * 4 + g) ^ (cn & 7);
        int aidx = row * 64 + slot * 8;
        ah[mt] = *(const half8*)&Ahi[aidx];
        al[mt] = *(const half8*)&Alo[aidx];
      }
#pragma unroll
      for (int nt = 0; nt < 4; ++nt) {
        size_t boff = ((size_t)(kt * 16 + w * 4 + nt) * 64 + l) * 8;
        half8 bh = *(const half8*)(Whi + boff);
        half8 bl = *(const half8*)(Wlo + boff);
#pragma unroll
        for (int mt = 0; mt < 4; ++mt) {
          acc[mt][nt] = __builtin_amdgcn_mfma_f32_16x16x32_f16(ah[mt], bh, acc[mt][nt], 0, 0, 0);
          acc[mt][nt] = __builtin_amdgcn_mfma_f32_16x16x32_f16(al[mt], bh, acc[mt][nt], 0, 0, 0);
          acc[mt][nt] = __builtin_amdgcn_mfma_f32_16x16x32_f16(ah[mt], bl, acc[mt][nt], 0, 0, 0);
        }
      }
    }
    __syncthreads();
  }
  // ---- epilogue: h[row][col] = acc + b_comb[col] ----
#pragma unroll
  for (int nt = 0; nt < 4; ++nt) {
    int col = w * 64 + nt * 16 + cn;
    float bc = b_comb[col];
#pragma unroll
    for (int mt = 0; mt < 4; ++mt) {
      int rbase = row0 + mt * 16 + g * 4;
#pragma unroll
      for (int rr = 0; rr < 4; ++rr) {
        int row = rbase + rr;
        if (row < N_ENTC)
          h[(size_t)row * 256 + col] = acc[mt][nt][rr] + bc;
      }
    }
  }
}

// ---------------------------------------------------------------------------
// K_hinst: by linearity, instance rows are masked means of entity rows:
//   h[N+r]      = mean_{id valid} h[id]       (b_comb averages to itself)
//   s_node[N+r] = mean_{id valid} s_node[id]
// 4 rows/block, one wave per row, lane owns 4 channels (float4 gathers).
// ---------------------------------------------------------------------------
__global__ __launch_bounds__(256) void k_hinst(
    float* __restrict__ h, float* __restrict__ s_node,
    const int* __restrict__ ids)
{
  int tid = threadIdx.x;
  int r = blockIdx.x * 4 + (tid >> 6);
  int l = tid & 63;
  int ch = l * 4;
  if (r >= N_ROWC) return;
  float4 s = make_float4(0.f, 0.f, 0.f, 0.f);
  float sn0 = 0.f, sn1 = 0.f;
  int cnt = 0;
#pragma unroll
  for (int k = 0; k < K_INSTC; ++k) {
    int id = ids[r * K_INSTC + k];
    if (id >= 0) {
      float4 v = *(const float4*)(h + (size_t)id * 256 + ch);
      s.x += v.x; s.y += v.y; s.z += v.z; s.w += v.w;
      if (l == 0) {
        sn0 += s_node[(size_t)id * 2 + 0];
        sn1 += s_node[(size_t)id * 2 + 1];
      }
      cnt++;
    }
  }
  float inv = 1.f / (float)cnt;   // cnt >= 1 guaranteed
  float4 o; o.x = s.x * inv; o.y = s.y * inv; o.z = s.z * inv; o.w = s.w * inv;
  *(float4*)(h + (size_t)(N_ENTC + r) * 256 + ch) = o;
  if (l == 0) {
    s_node[(size_t)(N_ENTC + r) * 2 + 0] = sn0 * inv;
    s_node[(size_t)(N_ENTC + r) * 2 + 1] = sn1 * inv;
  }
}

// ---------------------------------------------------------------------------
// K4a: per-edge alphas (tanh), Dn scatter, and packed bucket fill.
//   bE[slot] = {instRow, 0, bits(0.5*a10*a20), bits(0.5*a11*a21)} (one 16B slot)
//   Self term (0.5*a2^2*h_t) is folded analytically into k_gather.
// ---------------------------------------------------------------------------
__global__ __launch_bounds__(256) void k_alpha(
    const int* __restrict__ ei0, const int* __restrict__ ei1,
    const int* __restrict__ etype,
    const float* __restrict__ s_node, const float* __restrict__ s_edge_tab,
    float* __restrict__ Dn, int* __restrict__ cnt,
    int4* __restrict__ bE)
{
  int e = blockIdx.x * 256 + threadIdx.x;
  if (e >= N_EDGEC) return;
  int t = ei0[e], rI = ei1[e], ty = etype[e];
  float se0 = s_edge_tab[ty * 2 + 0], se1 = s_edge_tab[ty * 2 + 1];
  const float* snI = &s_node[(size_t)(N_ENTC + rI) * 2];
  const float* snT = &s_node[(size_t)t * 2];
  float a10 = tanhf(snI[0] + se0);
  float a11 = tanhf(snI[1] + se1);
  float a20 = tanhf(snT[0] + se0);
  float a21 = tanhf(snT[1] + se1);
  atomicAdd(&Dn[t * 2 + 0], a20 * a20);
  atomicAdd(&Dn[t * 2 + 1], a21 * a21);
  int pos = atomicAdd(&cnt[t], 1);
  if (pos < CAPB) {
    int4 ee;
    ee.x = rI; ee.y = 0;
    ee.z = __float_as_int(0.5f * a10 * a20);
    ee.w = __float_as_int(0.5f * a11 * a21);
    bE[(size_t)t * CAPB + pos] = ee;
  }
}

// ---------------------------------------------------------------------------
// K_gather: fused diffusion gather + finalize.
//   out = Dinv * sum_e c_j * h[instRow] + (dn>0 ? 1.5 : 1.0)*h_t + conv_bias
//   -> ELU -> + mod_bias -> prebn stored IN PLACE into h[:N].
// 4 waves/block, each wave sequentially owns EPB/4 entities; lane owns 4
// channels (float4). EPB=32 -> 3125 blocks = 12.5K independent latency
// chains. BN stats: per-thread doubles -> LDS cross-wave reduce -> 512
// atomics/block.
// ---------------------------------------------------------------------------
#define EPB 32    // entities per block (8 per wave)
__global__ __launch_bounds__(256) void k_gather(
    float* h, const float* __restrict__ Dn,
    const int* __restrict__ cnt, const int4* __restrict__ bE,
    const float* __restrict__ conv_bias, const float* __restrict__ mod_bias,
    double* __restrict__ bnacc)
{
  __shared__ double red[4][512];
  int tid = threadIdx.x;
  int wv = tid >> 6, l = tid & 63;
  int ch = l * 4;                 // base channel 0..252
  int j = l >> 5;                 // head
  float4 cb = *(const float4*)(conv_bias + (ch & 127));
  float4 mb = *(const float4*)(mod_bias + ch);
  double s0 = 0, s1 = 0, s2 = 0, s3 = 0;
  double q0 = 0, q1 = 0, q2 = 0, q3 = 0;
  int tbase = blockIdx.x * EPB + wv * (EPB / 4);
  for (int i = 0; i < EPB / 4; ++i) {
    int t = tbase + i;
    if (t >= N_ENTC) break;
    int deg = cnt[t]; deg = (deg < CAPB) ? deg : CAPB;
    float dn = Dn[t * 2 + j];
    float dinv = (dn > 0.f) ? (1.0f / dn) : 0.f;
    float sf = (dn > 0.f) ? 1.5f : 1.0f;     // 0.5*ht self-term + residual ht
    float4 cr = make_float4(0.f, 0.f, 0.f, 0.f);
    const int4* be = bE + (size_t)t * CAPB;
    for (int k = 0; k < deg; ++k) {
      int4 ee = be[k];
      float c = (l < 32) ? __int_as_float(ee.z) : __int_as_float(ee.w);
      float4 hv = *(const float4*)(h + (size_t)(N_ENTC + ee.x) * 256 + ch);
      cr.x += c * hv.x; cr.y += c * hv.y; cr.z += c * hv.z; cr.w += c * hv.w;
    }
    size_t idx = (size_t)t * 256 + ch;
    float4 ht = *(const float4*)(h + idx);
    float4 o;
    o.x = dinv * cr.x + sf * ht.x + cb.x;
    o.y = dinv * cr.y + sf * ht.y + cb.y;
    o.z = dinv * cr.z + sf * ht.z + cb.z;
    o.w = dinv * cr.w + sf * ht.w + cb.w;
    o.x = (o.x > 0.f) ? o.x : expm1f(o.x);
    o.y = (o.y > 0.f) ? o.y : expm1f(o.y);
    o.z = (o.z > 0.f) ? o.z : expm1f(o.z);
    o.w = (o.w > 0.f) ? o.w : expm1f(o.w);
    o.x += mb.x; o.y += mb.y; o.z += mb.z; o.w += mb.w;
    *(float4*)(h + idx) = o;                 // prebn in place
    s0 += (double)o.x; q0 += (double)o.x * (double)o.x;
    s1 += (double)o.y; q1 += (double)o.y * (double)o.y;
    s2 += (double)o.z; q2 += (double)o.z * (double)o.z;
    s3 += (double)o.w; q3 += (double)o.w * (double)o.w;
  }
  red[wv][ch + 0] = s0; red[wv][ch + 1] = s1;
  red[wv][ch + 2] = s2; red[wv][ch + 3] = s3;
  red[wv][256 + ch + 0] = q0; red[wv][256 + ch + 1] = q1;
  red[wv][256 + ch + 2] = q2; red[wv][256 + ch + 3] = q3;
  __syncthreads();
  double ssum = red[0][tid] + red[1][tid] + red[2][tid] + red[3][tid];
  double qsum = red[0][256 + tid] + red[1][256 + tid]
              + red[2][256 + tid] + red[3][256 + tid];
  atomicAdd(&bnacc[tid], ssum);
  atomicAdd(&bnacc[256 + tid], qsum);
}

// ---------------------------------------------------------------------------
// K6: BN affine coefficients (biased var, eps=1e-5)
// ---------------------------------------------------------------------------
__global__ void k_bnstat(const double* __restrict__ bnacc,
                         const float* __restrict__ gamma, const float* __restrict__ beta,
                         float* __restrict__ ss)
{
  int c = threadIdx.x;
  double mu  = bnacc[c] / (double)N_ENTC;
  double var = bnacc[256 + c] / (double)N_ENTC - mu * mu;
  double istd = 1.0 / sqrt(var + 1e-5);
  float sc = (float)((double)gamma[c] * istd);
  float sh = (float)((double)beta[c] - mu * (double)sc);
  ss[c] = sc; ss[256 + c] = sh;
}

// ---------------------------------------------------------------------------
// K7: normalize + fp32 store of out_ent  (prebn lives in h[:N])
// ---------------------------------------------------------------------------
__global__ __launch_bounds__(256) void k_store(
    const float* __restrict__ prebn, const float* __restrict__ ss,
    float* __restrict__ out)
{
  size_t stride = (size_t)gridDim.x * 256 * 4;
  for (size_t i = ((size_t)blockIdx.x * 256 + threadIdx.x) * 4;
       i < (size_t)N_ENTC * 256; i += stride) {
    float4 a = *(const float4*)(prebn + i);
    int c = (int)(i & 255);
    float4 o;
    o.x = a.x * ss[c + 0] + ss[256 + c + 0];
    o.y = a.y * ss[c + 1] + ss[256 + c + 1];
    o.z = a.z * ss[c + 2] + ss[256 + c + 2];
    o.w = a.w * ss[c + 3] + ss[256 + c + 3];
    *(float4*)(out + i) = o;
  }
}

// ---------------------------------------------------------------------------
// Workspace layout:
//   h       [0, 133,120,000)              fp32; [0:N) entity rows (-> prebn),
//                                         [N:NTOT) instance rows (k_hinst)
//   Dn      [133,120,000, +800,000)       zeroed by memset #1
//   bnacc   [133,920,000, +4,096)         zeroed by memset #1
//   cnt     [133,924,096, +400,000)       zeroed by memset #1
//   s_node  [134,324,096, +1,040,000)
//   ss      [135,364,096, +2,048)
//   s_edge  [135,366,144, +2,048)
//   BIG     [135,368,192, +102,400,000)
//     phase A (until k_gemm done):
//       Whi    @ +30,720,000 (131,072)
//       Wlo    @ +30,851,072 (131,072)
//       b_comb @ +30,982,144 (1,024)
//       w_s    @ +30,983,168 (2,064)
//     phase B (k_alpha onward; phase A dead):
//       bE     @ +0          (102,400,000)  int4[100K*64] packed {rI,_,c0,c1}
// ---------------------------------------------------------------------------
extern "C" void kernel_launch(void* const* d_in, const int* in_sizes, int n_in,
                              void* d_out, int out_size, void* d_ws, size_t ws_size,
                              hipStream_t stream)
{
  (void)in_sizes; (void)n_in; (void)out_size; (void)ws_size;

  const float* x         = (const float*)d_in[0];
  const int*   edge_idx  = (const int*)d_in[1];
  // d_in[2] = edge_order (unused)
  const int*   etype     = (const int*)d_in[3];
  const float* rel_embed = (const float*)d_in[4];
  const int*   ids       = (const int*)d_in[5];
  const float* W_in      = (const float*)d_in[6];
  const float* b_in      = (const float*)d_in[7];
  const float* W_edge    = (const float*)d_in[8];
  const float* b_edge    = (const float*)d_in[9];
  const float* W_sheaf   = (const float*)d_in[10];
  const float* b_sheaf   = (const float*)d_in[11];
  const float* W_conv    = (const float*)d_in[12];
  const float* b_conv    = (const float*)d_in[13];
  const float* conv_bias = (const float*)d_in[14];
  const float* w_rel     = (const float*)d_in[15];
  const float* loop_rel  = (const float*)d_in[16];
  const float* mod_bias  = (const float*)d_in[17];
  const float* bn_gamma  = (const float*)d_in[18];
  const float* bn_beta   = (const float*)d_in[19];

  const int* ei0 = edge_idx;            // target entities
  const int* ei1 = edge_idx + N_EDGEC;  // source instance rows

  char* ws = (char*)d_ws;
  const size_t OFF_H     = 0;
  const size_t OFF_DN    = OFF_H     + (size_t)NTOTC * 256 * 4;   // 133,120,000
  const size_t OFF_BN    = OFF_DN    + (size_t)N_ENTC * 2 * 4;    // +800,000
  const size_t OFF_CNT   = OFF_BN    + 4096;
  const size_t OFF_SNODE = OFF_CNT   + (size_t)N_ENTC * 4;
  const size_t OFF_SS    = OFF_SNODE + (size_t)NTOTC * 2 * 4;
  const size_t OFF_SEDGE = OFF_SS    + 2048;
  const size_t OFF_BIG   = OFF_SEDGE + 2048;
  const size_t OFF_WHI   = OFF_BIG   + (size_t)N_ROWC * 256 * 4;
  const size_t OFF_WLO   = OFF_WHI   + 131072;
  const size_t OFF_BC    = OFF_WLO   + 131072;
  const size_t OFF_WS    = OFF_BC    + 1024;
  const size_t OFF_BE    = OFF_BIG;                               // phase B

  float*     h       = (float*)(ws + OFF_H);
  float*     Dn      = (float*)(ws + OFF_DN);
  double*    bnacc   = (double*)(ws + OFF_BN);
  int*       cnt     = (int*)(ws + OFF_CNT);
  float*     s_node  = (float*)(ws + OFF_SNODE);
  float*     ss      = (float*)(ws + OFF_SS);
  float*     s_edge  = (float*)(ws + OFF_SEDGE);
  _Float16*  Whi     = (_Float16*)(ws + OFF_WHI);
  _Float16*  Wlo     = (_Float16*)(ws + OFF_WLO);
  float*     b_comb  = (float*)(ws + OFF_BC);
  float*     w_s     = (float*)(ws + OFF_WS);
  int4*      bE      = (int4*)(ws + OFF_BE);     // phase B overlay

  float* out_ent = (float*)d_out;
  float* out_rel = (float*)d_out + (size_t)N_ENTC * 256;

  // memset #1: Dn + bnacc + cnt (contiguous)
  hipMemsetAsync(ws + OFF_DN, 0,
                 (size_t)N_ENTC * 2 * 4 + 4096 + (size_t)N_ENTC * 4, stream);

  k_rel<<<201, 256, 0, stream>>>(rel_embed, loop_rel, W_edge, b_edge,
                                 W_sheaf, b_sheaf, w_rel, s_edge, out_rel);
  k_fuse<<<257, 256, 0, stream>>>(W_in, b_in, W_conv, b_conv, W_sheaf,
                                  Whi, Wlo, b_comb, w_s);
  k_snode<<<(N_ENTC + 63) / 64, 256, 0, stream>>>(x, w_s, s_node);
  k_gemm<<<(N_ENTC + 63) / 64, 256, 0, stream>>>(x, Whi, Wlo, b_comb, h);
  k_hinst<<<(N_ROWC + 3) / 4, 256, 0, stream>>>(h, s_node, ids);

  k_alpha<<<(N_EDGEC + 255) / 256, 256, 0, stream>>>(ei0, ei1, etype,
                                                     s_node, s_edge,
                                                     Dn, cnt, bE);
  k_gather<<<(N_ENTC + EPB - 1) / EPB, 256, 0, stream>>>(h, Dn, cnt, bE,
                                                         conv_bias, mod_bias,
                                                         bnacc);
  k_bnstat<<<1, 256, 0, stream>>>(bnacc, bn_gamma, bn_beta, ss);
  k_store<<<8192, 256, 0, stream>>>(h, ss, out_ent);
}

// Round 8
// 519.773 us; speedup vs baseline: 1.1818x; 1.0339x over previous
//
#include <hip/hip_runtime.h>
#include <stdint.h>

#define N_ENTC   100000
#define N_ROWC   30000
#define K_INSTC  8
#define N_EDGEC  200000
#define N_RELSC  200          // rel_full has 201 rows (loop_rel appended)
#define NTOTC    (N_ENTC + N_ROWC)   // 130000
#define CAPB     64           // bucket capacity per target entity (deg~Poisson(2))

typedef _Float16 half8  __attribute__((ext_vector_type(8)));
typedef _Float16 half4v __attribute__((ext_vector_type(4)));
typedef float    float4v __attribute__((ext_vector_type(4)));

// ---------------------------------------------------------------------------
// K1: per-relation-type table  s_edge_tab[t][j] = e_mean_t . W_sheaf[128:,j] + b_sheaf[j]
//     and r_out = rel_embed @ w_rel  (written straight to d_out tail, fp32)
// ---------------------------------------------------------------------------
__global__ __launch_bounds__(256) void k_rel(
    const float* __restrict__ rel_embed, const float* __restrict__ loop_rel,
    const float* __restrict__ W_edge,    const float* __restrict__ b_edge,
    const float* __restrict__ W_sheaf,   const float* __restrict__ b_sheaf,
    const float* __restrict__ w_rel,
    float* __restrict__ s_edge_tab, float* __restrict__ out_rel)
{
  __shared__ float rel[256];
  __shared__ float eproj[256];
  __shared__ float em[128];
  int t = blockIdx.x;        // 0..200
  int c = threadIdx.x;       // 0..255
  rel[c] = (t < N_RELSC) ? rel_embed[t * 256 + c] : loop_rel[c];
  __syncthreads();
  float acc = b_edge[c];
  for (int k = 0; k < 256; ++k) acc += rel[k] * W_edge[k * 256 + c];
  eproj[c] = acc;
  __syncthreads();
  if (c < 128) em[c] = 0.5f * (eproj[c] + eproj[c + 128]);
  __syncthreads();
  if (c < 2) {
    float s = b_sheaf[c];
    for (int hh = 0; hh < 128; ++hh) s += em[hh] * W_sheaf[(128 + hh) * 2 + c];
    s_edge_tab[t * 2 + c] = s;
  }
  if (t < N_RELSC) {
    float ro = 0.f;
    for (int k = 0; k < 256; ++k) ro += rel[k] * w_rel[k * 256 + c];
    out_rel[t * 256 + c] = ro;
  }
}

// ---------------------------------------------------------------------------
// K_fuse: fold the two linear layers into one weight matrix.
//   W_comb[k][n] = sum_c W_in[k][ (n>>7)*128 + c ] * W_conv[c][ n&127 ]
//   b_comb[n]   = (b_in @ blockdiag(W_conv))[n] + b_conv[n&127]
//   w_s[k][j]   = sum_hh 0.5*(W_in[k][hh]+W_in[k][hh+128]) * W_sheaf[hh][j]
//   c_s[j]      = same with b_in                      (stored at w_s[512+j])
// W_comb is split fp16 hi/lo and stored in MFMA B-fragment layout:
//   frag(kt,ntile): lane l holds B[kt*32 + 8*(l>>4)+e][ntile*16 + (l&15)],
//   element offset = ((kt*16+ntile)*64 + l)*8 + e.
// ---------------------------------------------------------------------------
__global__ __launch_bounds__(256) void k_fuse(
    const float* __restrict__ W_in,  const float* __restrict__ b_in,
    const float* __restrict__ W_conv, const float* __restrict__ b_conv,
    const float* __restrict__ W_sheaf,
    _Float16* __restrict__ Whi, _Float16* __restrict__ Wlo,
    float* __restrict__ b_comb, float* __restrict__ w_s)
{
  __shared__ float win[256];
  int k = blockIdx.x;            // 0..256
  int n = threadIdx.x;           // 0..255
  const float* src = (k < 256) ? (W_in + (size_t)k * 256) : b_in;
  win[n] = src[n];
  __syncthreads();
  int j = n >> 7, hh = n & 127;
  float acc = 0.f;
  for (int c = 0; c < 128; ++c)
    acc += win[j * 128 + c] * W_conv[c * 128 + hh];
  if (k < 256) {
    _Float16 hi = (_Float16)acc;
    _Float16 lo = (_Float16)(acc - (float)hi);
    int kt = k >> 5, g = (k >> 3) & 3, e = k & 7;
    int idx = ((kt * 16 + (n >> 4)) * 64 + (g * 16 + (n & 15))) * 8 + e;
    Whi[idx] = hi; Wlo[idx] = lo;
    if (n < 2) {
      float s = 0.f;
      for (int c2 = 0; c2 < 128; ++c2)
        s += 0.5f * (win[c2] + win[c2 + 128]) * W_sheaf[c2 * 2 + n];
      w_s[k * 2 + n] = s;
    }
  } else {
    b_comb[n] = acc + b_conv[hh];
    if (n < 2) {
      float s = 0.f;
      for (int c2 = 0; c2 < 128; ++c2)
        s += 0.5f * (win[c2] + win[c2 + 128]) * W_sheaf[c2 * 2 + n];
      w_s[512 + n] = s;          // c_s
    }
  }
}

// ---------------------------------------------------------------------------
// K_snode: s_node[row][j] = x[row] . w_s[:,j] + c_s[j]   (fp32, 2 cols)
// ENTITY ROWS ONLY (instance rows derived in k_hinst by linearity).
// Scheduled BEFORE k_gemm: also warms x into LLC.
// ---------------------------------------------------------------------------
__global__ __launch_bounds__(256) void k_snode(
    const float* __restrict__ x,
    const float* __restrict__ w_s, float* __restrict__ s_node)
{
  __shared__ float ws[514];
  int tid = threadIdx.x;
  for (int i = tid; i < 514; i += 256) ws[i] = w_s[i];
  __syncthreads();
  int r = tid >> 2, q = tid & 3;
  int row = blockIdx.x * 64 + r;
  if (row >= N_ENTC) return;    // whole 4-lane group exits together
  const float* src = x + (size_t)row * 256;
  float s0 = 0.f, s1 = 0.f;
  int kbase = q * 64;
#pragma unroll
  for (int i = 0; i < 16; ++i) {
    float4 v = *(const float4*)(src + kbase + i * 4);
    int k2 = (kbase + i * 4) * 2;
    s0 += v.x * ws[k2 + 0] + v.y * ws[k2 + 2] + v.z * ws[k2 + 4] + v.w * ws[k2 + 6];
    s1 += v.x * ws[k2 + 1] + v.y * ws[k2 + 3] + v.z * ws[k2 + 5] + v.w * ws[k2 + 7];
  }
  s0 += __shfl_xor(s0, 1); s0 += __shfl_xor(s0, 2);
  s1 += __shfl_xor(s1, 1); s1 += __shfl_xor(s1, 2);
  if (q < 2) {
    float val = (q == 0) ? s0 : s1;
    s_node[(size_t)row * 2 + q] = val + ws[512 + q];
  }
}

// ---------------------------------------------------------------------------
// K_gemm: h[0:N_ENTC] = x @ W_comb + b_comb via fp16 split-precision MFMA.
//   3-term Ootomo split: acc += Ahi*Bhi + Alo*Bhi + Ahi*Blo  (~fp32 accuracy)
//   R5-measured structure (109us @130K rows, 0 bank conflicts), entity rows.
// ---------------------------------------------------------------------------
__global__ __launch_bounds__(256, 3) void k_gemm(
    const float* __restrict__ x,
    const _Float16* __restrict__ Whi, const _Float16* __restrict__ Wlo,
    const float* __restrict__ b_comb,
    float* __restrict__ h)
{
  __shared__ _Float16 Ahi[64 * 64];
  __shared__ _Float16 Alo[64 * 64];

  int tid = threadIdx.x;
  int l = tid & 63;            // lane
  int w = tid >> 6;            // wave 0..3 -> col stripe w*64
  int row0 = blockIdx.x * 64;
  int g = l >> 4;              // fragment k-group
  int cn = l & 15;             // fragment row/col within 16

  float4v acc[4][4];
#pragma unroll
  for (int a = 0; a < 4; ++a)
#pragma unroll
    for (int b = 0; b < 4; ++b) acc[a][b] = (float4v)(0.f);

  int rs = tid >> 4;           // staging: row residue 0..15
  int kb = (tid & 15) * 4;     // staging: 4-float k chunk

  for (int ks = 0; ks < 4; ++ks) {
    int k0 = ks * 64;
    // ---- stage A tile (64 rows x 64 k), fp32 -> fp16 hi/lo, swizzled ----
#pragma unroll
    for (int i = 0; i < 4; ++i) {
      int r = rs + i * 16;
      int row = row0 + r;
      float4 v = make_float4(0.f, 0.f, 0.f, 0.f);
      if (row < N_ENTC) {
        v = *(const float4*)(x + (size_t)row * 256 + k0 + kb);
      }
      half4v hv, lv;
      hv[0] = (_Float16)v.x; lv[0] = (_Float16)(v.x - (float)hv[0]);
      hv[1] = (_Float16)v.y; lv[1] = (_Float16)(v.y - (float)hv[1]);
      hv[2] = (_Float16)v.z; lv[2] = (_Float16)(v.z - (float)hv[2]);
      hv[3] = (_Float16)v.w; lv[3] = (_Float16)(v.w - (float)hv[3]);
      int idx = r * 64 + (((kb >> 3) ^ (r & 7)) << 3) + (kb & 7);
      *(half4v*)&Ahi[idx] = hv;
      *(half4v*)&Alo[idx] = lv;
    }
    __syncthreads();
    // ---- compute ----
#pragma unroll
    for (int kf = 0; kf < 2; ++kf) {
      int kt = ks * 2 + kf;
      half8 ah[4], al[4];
#pragma unroll
      for (int mt = 0; mt < 4; ++mt) {
        int row = mt * 16 + cn;
        int slot = (kf * 4 + g) ^ (cn & 7);
        int aidx = row * 64 + slot * 8;
        ah[mt] = *(const half8*)&Ahi[aidx];
        al[mt] = *(const half8*)&Alo[aidx];
      }
#pragma unroll
      for (int nt = 0; nt < 4; ++nt) {
        size_t boff = ((size_t)(kt * 16 + w * 4 + nt) * 64 + l) * 8;
        half8 bh = *(const half8*)(Whi + boff);
        half8 bl = *(const half8*)(Wlo + boff);
#pragma unroll
        for (int mt = 0; mt < 4; ++mt) {
          acc[mt][nt] = __builtin_amdgcn_mfma_f32_16x16x32_f16(ah[mt], bh, acc[mt][nt], 0, 0, 0);
          acc[mt][nt] = __builtin_amdgcn_mfma_f32_16x16x32_f16(al[mt], bh, acc[mt][nt], 0, 0, 0);
          acc[mt][nt] = __builtin_amdgcn_mfma_f32_16x16x32_f16(ah[mt], bl, acc[mt][nt], 0, 0, 0);
        }
      }
    }
    __syncthreads();
  }
  // ---- epilogue: h[row][col] = acc + b_comb[col] ----
#pragma unroll
  for (int nt = 0; nt < 4; ++nt) {
    int col = w * 64 + nt * 16 + cn;
    float bc = b_comb[col];
#pragma unroll
    for (int mt = 0; mt < 4; ++mt) {
      int rbase = row0 + mt * 16 + g * 4;
#pragma unroll
      for (int rr = 0; rr < 4; ++rr) {
        int row = rbase + rr;
        if (row < N_ENTC)
          h[(size_t)row * 256 + col] = acc[mt][nt][rr] + bc;
      }
    }
  }
}

// ---------------------------------------------------------------------------
// K_hinst: by linearity, instance rows are masked means of entity rows:
//   h[N+r]      = mean_{id valid} h[id]       (b_comb averages to itself)
//   s_node[N+r] = mean_{id valid} s_node[id]
// Branchless clamped gathers (id<0 -> row 0, weight 0): all 8 loads are
// unconditional and independent -> compiler hoists them, no divergence.
// ---------------------------------------------------------------------------
__global__ __launch_bounds__(256) void k_hinst(
    float* __restrict__ h, float* __restrict__ s_node,
    const int* __restrict__ ids)
{
  int tid = threadIdx.x;
  int r = blockIdx.x * 4 + (tid >> 6);
  int l = tid & 63;
  int ch = l * 4;
  if (r >= N_ROWC) return;
  float4 s = make_float4(0.f, 0.f, 0.f, 0.f);
  float sn0 = 0.f, sn1 = 0.f;
  int cnt = 0;
#pragma unroll
  for (int k = 0; k < K_INSTC; ++k) {
    int id = ids[r * K_INSTC + k];
    int idc = (id >= 0) ? id : 0;
    float wt = (id >= 0) ? 1.f : 0.f;
    float4 v = *(const float4*)(h + (size_t)idc * 256 + ch);
    s.x += wt * v.x; s.y += wt * v.y; s.z += wt * v.z; s.w += wt * v.w;
    if (l == 0) {
      sn0 += wt * s_node[(size_t)idc * 2 + 0];
      sn1 += wt * s_node[(size_t)idc * 2 + 1];
    }
    cnt += (id >= 0) ? 1 : 0;
  }
  float inv = 1.f / (float)cnt;   // cnt >= 1 guaranteed
  float4 o; o.x = s.x * inv; o.y = s.y * inv; o.z = s.z * inv; o.w = s.w * inv;
  *(float4*)(h + (size_t)(N_ENTC + r) * 256 + ch) = o;
  if (l == 0) {
    s_node[(size_t)(N_ENTC + r) * 2 + 0] = sn0 * inv;
    s_node[(size_t)(N_ENTC + r) * 2 + 1] = sn1 * inv;
  }
}

// ---------------------------------------------------------------------------
// K4a: per-edge alphas (tanh), Dn scatter, and packed bucket fill.
//   bE[slot] = {instRow, 0, bits(0.5*a10*a20), bits(0.5*a11*a21)} (one 16B slot)
//   Self term (0.5*a2^2*h_t) is folded analytically into k_gather.
// ---------------------------------------------------------------------------
__global__ __launch_bounds__(256) void k_alpha(
    const int* __restrict__ ei0, const int* __restrict__ ei1,
    const int* __restrict__ etype,
    const float* __restrict__ s_node, const float* __restrict__ s_edge_tab,
    float* __restrict__ Dn, int* __restrict__ cnt,
    int4* __restrict__ bE)
{
  int e = blockIdx.x * 256 + threadIdx.x;
  if (e >= N_EDGEC) return;
  int t = ei0[e], rI = ei1[e], ty = etype[e];
  float se0 = s_edge_tab[ty * 2 + 0], se1 = s_edge_tab[ty * 2 + 1];
  const float* snI = &s_node[(size_t)(N_ENTC + rI) * 2];
  const float* snT = &s_node[(size_t)t * 2];
  float a10 = tanhf(snI[0] + se0);
  float a11 = tanhf(snI[1] + se1);
  float a20 = tanhf(snT[0] + se0);
  float a21 = tanhf(snT[1] + se1);
  atomicAdd(&Dn[t * 2 + 0], a20 * a20);
  atomicAdd(&Dn[t * 2 + 1], a21 * a21);
  int pos = atomicAdd(&cnt[t], 1);
  if (pos < CAPB) {
    int4 ee;
    ee.x = rI; ee.y = 0;
    ee.z = __float_as_int(0.5f * a10 * a20);
    ee.w = __float_as_int(0.5f * a11 * a21);
    bE[(size_t)t * CAPB + pos] = ee;
  }
}

// ---------------------------------------------------------------------------
// K_gather: fused diffusion gather + finalize.
//   out = Dinv * sum_e c_j * h[instRow] + (dn>0 ? 1.5 : 1.0)*h_t + conv_bias
//   -> ELU -> + mod_bias -> prebn stored IN PLACE into h[:N].
// ILP restructure (R8): per wave, 2 batches of 8 entities. Phase A preloads
// descriptors (cnt, Dn, bucket slots 0+1) for all 8 -- independent loads.
// Phase B issues the h-gathers for all 8 with zero-coefficient clamping for
// deg<2 (reads of unused workspace slots are safe; coefficient 0 nullifies).
// ~16 independent 1KB gathers in flight per wave vs ~2 in the serial form.
// Tail (deg>2, ~32% of entities, Poisson(2)) handled by a short loop.
// EPB back to 64 (R5-measured better than 32). VGPR rises (~140) and
// occupancy drops -- intended ILP-for-TLP trade.
// ---------------------------------------------------------------------------
#define EPB 64    // entities per block (16 per wave, 2 batches of 8)
__global__ __launch_bounds__(256) void k_gather(
    float* h, const float* __restrict__ Dn,
    const int* __restrict__ cnt, const int4* __restrict__ bE,
    const float* __restrict__ conv_bias, const float* __restrict__ mod_bias,
    double* __restrict__ bnacc)
{
  __shared__ double red[4][512];
  int tid = threadIdx.x;
  int wv = tid >> 6, l = tid & 63;
  int ch = l * 4;                 // base channel 0..252
  int j = l >> 5;                 // head
  float4 cb = *(const float4*)(conv_bias + (ch & 127));
  float4 mb = *(const float4*)(mod_bias + ch);
  double s0 = 0, s1 = 0, s2 = 0, s3 = 0;
  double q0 = 0, q1 = 0, q2 = 0, q3 = 0;
  int tbase = blockIdx.x * EPB + wv * 16;
#pragma unroll
  for (int b = 0; b < 2; ++b) {
    int t0 = tbase + b * 8;
    int   dg[8]; float dnv[8]; int4 e0[8], e1[8];
    // ---- phase A: independent descriptor loads for 8 entities ----
#pragma unroll
    for (int i = 0; i < 8; ++i) {
      int t = t0 + i;
      int tc = (t < N_ENTC) ? t : (N_ENTC - 1);
      int d = cnt[tc]; dg[i] = (d < CAPB) ? d : CAPB;
      dnv[i] = Dn[tc * 2 + j];
      const int4* be = bE + (size_t)tc * CAPB;
      e0[i] = be[0];
      e1[i] = be[1];
    }
    // ---- phase B: gathers + finalize (independent across i) ----
#pragma unroll
    for (int i = 0; i < 8; ++i) {
      int t = t0 + i;
      bool valid = (t < N_ENTC);
      int tc = valid ? t : (N_ENTC - 1);
      float c0 = (dg[i] > 0)
          ? ((l < 32) ? __int_as_float(e0[i].z) : __int_as_float(e0[i].w)) : 0.f;
      float c1 = (dg[i] > 1)
          ? ((l < 32) ? __int_as_float(e1[i].z) : __int_as_float(e1[i].w)) : 0.f;
      int r0 = (dg[i] > 0) ? e0[i].x : 0;
      int r1 = (dg[i] > 1) ? e1[i].x : 0;
      float4 h0 = *(const float4*)(h + (size_t)(N_ENTC + r0) * 256 + ch);
      float4 h1 = *(const float4*)(h + (size_t)(N_ENTC + r1) * 256 + ch);
      float4 cr;
      cr.x = c0 * h0.x + c1 * h1.x;
      cr.y = c0 * h0.y + c1 * h1.y;
      cr.z = c0 * h0.z + c1 * h1.z;
      cr.w = c0 * h0.w + c1 * h1.w;
      if (dg[i] > 2) {
        const int4* be = bE + (size_t)tc * CAPB;
        for (int k = 2; k < dg[i]; ++k) {
          int4 ee = be[k];
          float c = (l < 32) ? __int_as_float(ee.z) : __int_as_float(ee.w);
          float4 hv = *(const float4*)(h + (size_t)(N_ENTC + ee.x) * 256 + ch);
          cr.x += c * hv.x; cr.y += c * hv.y;
          cr.z += c * hv.z; cr.w += c * hv.w;
        }
      }
      float dn = dnv[i];
      float dinv = (dn > 0.f) ? (1.0f / dn) : 0.f;
      float sf = (dn > 0.f) ? 1.5f : 1.0f;   // 0.5*ht self-term + residual ht
      size_t idx = (size_t)tc * 256 + ch;
      float4 ht = *(const float4*)(h + idx);
      float4 o;
      o.x = dinv * cr.x + sf * ht.x + cb.x;
      o.y = dinv * cr.y + sf * ht.y + cb.y;
      o.z = dinv * cr.z + sf * ht.z + cb.z;
      o.w = dinv * cr.w + sf * ht.w + cb.w;
      o.x = (o.x > 0.f) ? o.x : expm1f(o.x);
      o.y = (o.y > 0.f) ? o.y : expm1f(o.y);
      o.z = (o.z > 0.f) ? o.z : expm1f(o.z);
      o.w = (o.w > 0.f) ? o.w : expm1f(o.w);
      o.x += mb.x; o.y += mb.y; o.z += mb.z; o.w += mb.w;
      if (valid) {
        *(float4*)(h + idx) = o;             // prebn in place
        s0 += (double)o.x; q0 += (double)o.x * (double)o.x;
        s1 += (double)o.y; q1 += (double)o.y * (double)o.y;
        s2 += (double)o.z; q2 += (double)o.z * (double)o.z;
        s3 += (double)o.w; q3 += (double)o.w * (double)o.w;
      }
    }
  }
  red[wv][ch + 0] = s0; red[wv][ch + 1] = s1;
  red[wv][ch + 2] = s2; red[wv][ch + 3] = s3;
  red[wv][256 + ch + 0] = q0; red[wv][256 + ch + 1] = q1;
  red[wv][256 + ch + 2] = q2; red[wv][256 + ch + 3] = q3;
  __syncthreads();
  double ssum = red[0][tid] + red[1][tid] + red[2][tid] + red[3][tid];
  double qsum = red[0][256 + tid] + red[1][256 + tid]
              + red[2][256 + tid] + red[3][256 + tid];
  atomicAdd(&bnacc[tid], ssum);
  atomicAdd(&bnacc[256 + tid], qsum);
}

// ---------------------------------------------------------------------------
// K6: BN affine coefficients (biased var, eps=1e-5)
// ---------------------------------------------------------------------------
__global__ void k_bnstat(const double* __restrict__ bnacc,
                         const float* __restrict__ gamma, const float* __restrict__ beta,
                         float* __restrict__ ss)
{
  int c = threadIdx.x;
  double mu  = bnacc[c] / (double)N_ENTC;
  double var = bnacc[256 + c] / (double)N_ENTC - mu * mu;
  double istd = 1.0 / sqrt(var + 1e-5);
  float sc = (float)((double)gamma[c] * istd);
  float sh = (float)((double)beta[c] - mu * (double)sc);
  ss[c] = sc; ss[256 + c] = sh;
}

// ---------------------------------------------------------------------------
// K7: normalize + fp32 store of out_ent  (prebn lives in h[:N])
// ---------------------------------------------------------------------------
__global__ __launch_bounds__(256) void k_store(
    const float* __restrict__ prebn, const float* __restrict__ ss,
    float* __restrict__ out)
{
  size_t stride = (size_t)gridDim.x * 256 * 4;
  for (size_t i = ((size_t)blockIdx.x * 256 + threadIdx.x) * 4;
       i < (size_t)N_ENTC * 256; i += stride) {
    float4 a = *(const float4*)(prebn + i);
    int c = (int)(i & 255);
    float4 o;
    o.x = a.x * ss[c + 0] + ss[256 + c + 0];
    o.y = a.y * ss[c + 1] + ss[256 + c + 1];
    o.z = a.z * ss[c + 2] + ss[256 + c + 2];
    o.w = a.w * ss[c + 3] + ss[256 + c + 3];
    *(float4*)(out + i) = o;
  }
}

// ---------------------------------------------------------------------------
// Workspace layout:
//   h       [0, 133,120,000)              fp32; [0:N) entity rows (-> prebn),
//                                         [N:NTOT) instance rows (k_hinst)
//   Dn      [133,120,000, +800,000)       zeroed by memset #1
//   bnacc   [133,920,000, +4,096)         zeroed by memset #1
//   cnt     [133,924,096, +400,000)       zeroed by memset #1
//   s_node  [134,324,096, +1,040,000)
//   ss      [135,364,096, +2,048)
//   s_edge  [135,366,144, +2,048)
//   BIG     [135,368,192, +102,400,000)
//     phase A (until k_gemm done):
//       Whi    @ +30,720,000 (131,072)
//       Wlo    @ +30,851,072 (131,072)
//       b_comb @ +30,982,144 (1,024)
//       w_s    @ +30,983,168 (2,064)
//     phase B (k_alpha onward; phase A dead):
//       bE     @ +0          (102,400,000)  int4[100K*64] packed {rI,_,c0,c1}
// ---------------------------------------------------------------------------
extern "C" void kernel_launch(void* const* d_in, const int* in_sizes, int n_in,
                              void* d_out, int out_size, void* d_ws, size_t ws_size,
                              hipStream_t stream)
{
  (void)in_sizes; (void)n_in; (void)out_size; (void)ws_size;

  const float* x         = (const float*)d_in[0];
  const int*   edge_idx  = (const int*)d_in[1];
  // d_in[2] = edge_order (unused)
  const int*   etype     = (const int*)d_in[3];
  const float* rel_embed = (const float*)d_in[4];
  const int*   ids       = (const int*)d_in[5];
  const float* W_in      = (const float*)d_in[6];
  const float* b_in      = (const float*)d_in[7];
  const float* W_edge    = (const float*)d_in[8];
  const float* b_edge    = (const float*)d_in[9];
  const float* W_sheaf   = (const float*)d_in[10];
  const float* b_sheaf   = (const float*)d_in[11];
  const float* W_conv    = (const float*)d_in[12];
  const float* b_conv    = (const float*)d_in[13];
  const float* conv_bias = (const float*)d_in[14];
  const float* w_rel     = (const float*)d_in[15];
  const float* loop_rel  = (const float*)d_in[16];
  const float* mod_bias  = (const float*)d_in[17];
  const float* bn_gamma  = (const float*)d_in[18];
  const float* bn_beta   = (const float*)d_in[19];

  const int* ei0 = edge_idx;            // target entities
  const int* ei1 = edge_idx + N_EDGEC;  // source instance rows

  char* ws = (char*)d_ws;
  const size_t OFF_H     = 0;
  const size_t OFF_DN    = OFF_H     + (size_t)NTOTC * 256 * 4;   // 133,120,000
  const size_t OFF_BN    = OFF_DN    + (size_t)N_ENTC * 2 * 4;    // +800,000
  const size_t OFF_CNT   = OFF_BN    + 4096;
  const size_t OFF_SNODE = OFF_CNT   + (size_t)N_ENTC * 4;
  const size_t OFF_SS    = OFF_SNODE + (size_t)NTOTC * 2 * 4;
  const size_t OFF_SEDGE = OFF_SS    + 2048;
  const size_t OFF_BIG   = OFF_SEDGE + 2048;
  const size_t OFF_WHI   = OFF_BIG   + (size_t)N_ROWC * 256 * 4;
  const size_t OFF_WLO   = OFF_WHI   + 131072;
  const size_t OFF_BC    = OFF_WLO   + 131072;
  const size_t OFF_WS    = OFF_BC    + 1024;
  const size_t OFF_BE    = OFF_BIG;                               // phase B

  float*     h       = (float*)(ws + OFF_H);
  float*     Dn      = (float*)(ws + OFF_DN);
  double*    bnacc   = (double*)(ws + OFF_BN);
  int*       cnt     = (int*)(ws + OFF_CNT);
  float*     s_node  = (float*)(ws + OFF_SNODE);
  float*     ss      = (float*)(ws + OFF_SS);
  float*     s_edge  = (float*)(ws + OFF_SEDGE);
  _Float16*  Whi     = (_Float16*)(ws + OFF_WHI);
  _Float16*  Wlo     = (_Float16*)(ws + OFF_WLO);
  float*     b_comb  = (float*)(ws + OFF_BC);
  float*     w_s     = (float*)(ws + OFF_WS);
  int4*      bE      = (int4*)(ws + OFF_BE);     // phase B overlay

  float* out_ent = (float*)d_out;
  float* out_rel = (float*)d_out + (size_t)N_ENTC * 256;

  // memset #1: Dn + bnacc + cnt (contiguous)
  hipMemsetAsync(ws + OFF_DN, 0,
                 (size_t)N_ENTC * 2 * 4 + 4096 + (size_t)N_ENTC * 4, stream);

  k_rel<<<201, 256, 0, stream>>>(rel_embed, loop_rel, W_edge, b_edge,
                                 W_sheaf, b_sheaf, w_rel, s_edge, out_rel);
  k_fuse<<<257, 256, 0, stream>>>(W_in, b_in, W_conv, b_conv, W_sheaf,
                                  Whi, Wlo, b_comb, w_s);
  k_snode<<<(N_ENTC + 63) / 64, 256, 0, stream>>>(x, w_s, s_node);
  k_gemm<<<(N_ENTC + 63) / 64, 256, 0, stream>>>(x, Whi, Wlo, b_comb, h);
  k_hinst<<<(N_ROWC + 3) / 4, 256, 0, stream>>>(h, s_node, ids);

  k_alpha<<<(N_EDGEC + 255) / 256, 256, 0, stream>>>(ei0, ei1, etype,
                                                     s_node, s_edge,
                                                     Dn, cnt, bE);
  k_gather<<<(N_ENTC + EPB - 1) / EPB, 256, 0, stream>>>(h, Dn, cnt, bE,
                                                         conv_bias, mod_bias,
                                                         bnacc);
  k_bnstat<<<1, 256, 0, stream>>>(bnacc, bn_gamma, bn_beta, ss);
  k_store<<<8192, 256, 0, stream>>>(h, ss, out_ent);
}